// Round 8
// baseline (104.346 us; speedup 1.0000x reference)
//
#include <hip/hip_runtime.h>
#include <stdint.h>

typedef uint64_t u64;
typedef uint32_t u32;

#define NB    8
#define NQ    4096
#define NKEY  4096
#define CV    64
#define KSEL  16
#define G     8              /* queries per wave */
#define NWAVE 4              /* waves per block */
#define BLK   (NWAVE * 64)   /* 256 threads */
#define CMAX  64             /* candidate slots per query */
#define PADU  (~(u64)0)

__device__ __forceinline__ u64 shflxor_u64(u64 v, int m) {
    const u32 lo = __shfl_xor((int)(u32)v, m);
    const u32 hi = __shfl_xor((int)(u32)(v >> 32), m);
    return (((u64)hi) << 32) | lo;
}
__device__ __forceinline__ int mbcnt64(u64 m) {
    return (int)__builtin_amdgcn_mbcnt_hi((u32)(m >> 32),
               __builtin_amdgcn_mbcnt_lo((u32)m, 0));
}
/* monotone float -> u32 key (metric k2-2q.k can be negative) */
__device__ __forceinline__ u32 fkey(float f) {
    const u32 b = __float_as_uint(f);
    return b ^ (0x80000000u | (u32)((int32_t)b >> 31));
}

/* rolled 64-lane bitonic sort, ascending — ONE code copy (I$ discipline) */
__device__ __noinline__ float lanesort64_f32(float v, int lane) {
#pragma unroll 1
    for (int k = 2; k <= 64; k <<= 1) {
#pragma unroll 1
        for (int j = k >> 1; j > 0; j >>= 1) {
            const float p = __shfl_xor(v, j);
            const bool up    = ((lane & k) == 0);
            const bool lower = ((lane & j) == 0);
            v = (lower == up) ? fminf(v, p) : fmaxf(v, p);
        }
    }
    return v;
}

__device__ __noinline__ u64 lanesort64_u64(u64 v, int lane) {
#pragma unroll 1
    for (int k = 2; k <= 64; k <<= 1) {
#pragma unroll 1
        for (int j = k >> 1; j > 0; j >>= 1) {
            const u64 p = shflxor_u64(v, j);
            const bool up    = ((lane & k) == 0);
            const bool lower = ((lane & j) == 0);
            const u64 mn = v < p ? v : p, mx = v < p ? p : v;
            v = (lower == up) ? mn : mx;
        }
    }
    return v;
}

/* overflow fallback (~never runs; one code copy, called under uniform branch):
   exact rank-16 threshold via bit binary search, then recollect. */
__device__ __noinline__ int exact_recollect(const float4* __restrict__ kp4,
                                            int lane, float m2xq, float m2yq,
                                            u64* __restrict__ row) {
    u32 lo = 0, hi = ~0u;
#pragma unroll 1
    while (lo < hi) {
        const u32 mid = lo + ((hi - lo) >> 1);
        int cc = 0;
#pragma unroll 1
        for (int c = 0; c < 32; ++c) {
            const float4 kk = kp4[c * 64 + lane];
            const float k2a = fmaf(kk.x, kk.x, kk.y * kk.y);
            const float k2b = fmaf(kk.z, kk.z, kk.w * kk.w);
            const float va = fmaf(kk.x, m2xq, fmaf(kk.y, m2yq, k2a));
            const float vb = fmaf(kk.z, m2xq, fmaf(kk.w, m2yq, k2b));
            cc += (fkey(va) <= mid) ? 1 : 0;
            cc += (fkey(vb) <= mid) ? 1 : 0;
        }
#pragma unroll 1
        for (int off = 32; off; off >>= 1) cc += __shfl_xor(cc, off);
        if (cc >= KSEL) hi = mid; else lo = mid + 1;
    }
    int cc = 0;
#pragma unroll 1
    for (int c = 0; c < 32; ++c) {
        const float4 kk = kp4[c * 64 + lane];
        const float k2a = fmaf(kk.x, kk.x, kk.y * kk.y);
        const float k2b = fmaf(kk.z, kk.z, kk.w * kk.w);
        const float va = fmaf(kk.x, m2xq, fmaf(kk.y, m2yq, k2a));
        const float vb = fmaf(kk.z, m2xq, fmaf(kk.w, m2yq, k2b));
        const u32 ta = fkey(va), tb = fkey(vb);
        const bool aa = ta <= lo, ab = tb <= lo;
        const u64 mka = __ballot(aa);
        const u64 mkb = __ballot(ab);
        const int posa = cc + mbcnt64(mka);
        cc += (int)__popcll(mka);
        const int posb = cc + mbcnt64(mkb);
        cc += (int)__popcll(mkb);
        const u32 ia = (u32)(2 * (c * 64 + lane));
        if (aa && posa < CMAX) row[posa] = (((u64)ta) << 32) | ia;
        if (ab && posb < CMAX) row[posb] = (((u64)tb) << 32) | (ia + 1);
    }
    return cc < CMAX ? cc : CMAX;
}

/* setup: 9 query-independent affine sums over H=64 -> d_ws */
__global__ void setup_kernel(const float* __restrict__ qw, const float* __restrict__ qb,
                             const float* __restrict__ kw, const float* __restrict__ kb,
                             float* __restrict__ w9)
{
    const int h = threadIdx.x & 63;
    const float2 a = ((const float2*)qw)[h];
    const float2 c = ((const float2*)kw)[h];
    const float qbh = qb[h], kbh = kb[h];
    float s[9] = { a.x * c.x, a.y * c.x, qbh * c.x,
                   a.x * c.y, a.y * c.y, qbh * c.y,
                   a.x * kbh, a.y * kbh, qbh * kbh };
#pragma unroll
    for (int i = 0; i < 9; ++i)
#pragma unroll 1
        for (int off = 32; off; off >>= 1) s[i] += __shfl_xor(s[i], off);
    if (h == 0) {
#pragma unroll
        for (int i = 0; i < 9; ++i) w9[i] = s[i];
    }
}

extern "C" __global__ __launch_bounds__(BLK, 4) void bev_main(
    const float* __restrict__ qg, const float* __restrict__ kg,
    const float* __restrict__ vg, const float* __restrict__ w9,
    float* __restrict__ outg)
{
    __shared__ u64 cand[NWAVE][G][CMAX];      /* 16 KB; per-wave private */
    __shared__ int scnt[NWAVE][G];

    const int tid  = threadIdx.x;
    const int wv   = tid >> 6;
    const int lane = tid & 63;
    const int wvu  = __builtin_amdgcn_readfirstlane(wv);
    const int b    = blockIdx.x >> 7;                  /* 128 blocks per batch */
    const int qbase = ((int)(blockIdx.x & 127) * NWAVE + wvu) * G;

    const float2* kp  = (const float2*)(kg + (size_t)b * NKEY * 2);
    const float4* kp4 = (const float4*)kp;             /* 2 keys / 16 B */
    const float2* qp  = (const float2*)qg + (size_t)b * NQ + qbase;

    /* wave-uniform query coefs (used only with compile-time q -> SGPRs) */
    float m2x[G], m2y[G];
#pragma unroll
    for (int q = 0; q < G; ++q) {
        const float2 qc = qp[q];
        m2x[q] = -2.f * qc.x; m2y[q] = -2.f * qc.y;
    }

    /* ---- pass 1: per-lane metric-min per query (rolled c, unrolled q) ---- */
    float mn[G];
#pragma unroll
    for (int q = 0; q < G; ++q) mn[q] = __builtin_inff();
#pragma unroll 2
    for (int c = 0; c < 32; ++c) {
        const float4 kk = kp4[c * 64 + lane];
        const float k2a = fmaf(kk.x, kk.x, kk.y * kk.y);
        const float k2b = fmaf(kk.z, kk.z, kk.w * kk.w);
#pragma unroll
        for (int q = 0; q < G; ++q) {
            const float va = fmaf(kk.x, m2x[q], fmaf(kk.y, m2y[q], k2a));
            const float vb = fmaf(kk.z, m2x[q], fmaf(kk.w, m2y[q], k2b));
            mn[q] = fminf(mn[q], fminf(va, vb));
        }
    }

    /* ---- thresholds: 16th-smallest of 64 lane-mins (guarantees >=16) ---- */
    float thr[G];
#pragma unroll
    for (int q = 0; q < G; ++q)
        thr[q] = __shfl(lanesort64_f32(mn[q], lane), 15);

    /* ---- pass 2: recompute metric, ballot-append all <= thr ---- */
    int cnt[G];
#pragma unroll
    for (int q = 0; q < G; ++q) cnt[q] = 0;
#pragma unroll 1
    for (int c = 0; c < 32; ++c) {
        const float4 kk = kp4[c * 64 + lane];
        const float k2a = fmaf(kk.x, kk.x, kk.y * kk.y);
        const float k2b = fmaf(kk.z, kk.z, kk.w * kk.w);
        const u32 ia = (u32)(2 * (c * 64 + lane));
#pragma unroll
        for (int q = 0; q < G; ++q) {
            const float va = fmaf(kk.x, m2x[q], fmaf(kk.y, m2y[q], k2a));
            const float vb = fmaf(kk.z, m2x[q], fmaf(kk.w, m2y[q], k2b));
            const bool aa = va <= thr[q];
            const bool ab = vb <= thr[q];
            const u64 mka = __ballot(aa);
            const u64 mkb = __ballot(ab);
            if (mka | mkb) {                           /* uniform branch */
                const int posa = cnt[q] + mbcnt64(mka);
                cnt[q] += (int)__popcll(mka);
                const int posb = cnt[q] + mbcnt64(mkb);
                cnt[q] += (int)__popcll(mkb);
                if (aa && posa < CMAX)
                    cand[wv][q][posa] = (((u64)fkey(va)) << 32) | ia;
                if (ab && posb < CMAX)
                    cand[wv][q][posb] = (((u64)fkey(vb)) << 32) | (ia + 1);
            }
        }
    }
    if (lane == 0) {
#pragma unroll
        for (int q = 0; q < G; ++q) scnt[wv][q] = cnt[q];
    }

    /* ---- per query (rolled): exact top-16, scores, softmax, V gather ---- */
    const float s1 = w9[0], s2 = w9[1], s3 = w9[2];
    const float s4 = w9[3], s5 = w9[4], s6 = w9[5];
    const float s7 = w9[6], s8 = w9[7], s9 = w9[8];
    const float* vb = vg + (size_t)b * NKEY * CV;

#pragma unroll 1
    for (int q = 0; q < G; ++q) {
        const float2 qc = qp[q];                       /* uniform reload */
        int cn = scnt[wv][q];
        if (cn > CMAX)                                  /* ~never */
            cn = exact_recollect(kp4, lane, -2.f * qc.x, -2.f * qc.y,
                                 &cand[wv][q][0]);

        u64 myv = (lane < cn) ? cand[wv][q][lane] : PADU;
        myv = lanesort64_u64(myv, lane);
        const u32 myidx = (u32)myv;

        const float A  = fmaf(qc.x, s1, fmaf(qc.y, s2, s3));
        const float Bb = fmaf(qc.x, s4, fmaf(qc.y, s5, s6));
        const float Cc = fmaf(qc.x, s7, fmaf(qc.y, s8, s9));

        const int sel = (lane < KSEL) ? (int)myidx : 0;
        const float2 kc = kp[sel];
        const float score = fmaf(A, kc.x, fmaf(Bb, kc.y, Cc));
        float mx = score;
#pragma unroll 1
        for (int off = 8; off; off >>= 1) mx = fmaxf(mx, __shfl_xor(mx, off));
        const float e = __expf(score - mx);
        float sum = e;
#pragma unroll 1
        for (int off = 8; off; off >>= 1) sum += __shfl_xor(sum, off);
        const float w = e / sum;                       /* valid lanes 0..15 */

        float acc = 0.f;
#pragma unroll 4
        for (int s = 0; s < KSEL; ++s) {
            const u32 id   = (u32)__builtin_amdgcn_readlane((int)myidx, s);
            const float ws = __uint_as_float(
                (u32)__builtin_amdgcn_readlane((int)__float_as_uint(w), s));
            acc = fmaf(ws, vb[(size_t)id * CV + lane], acc);
        }
        outg[((size_t)b * NQ + qbase + q) * CV + lane] = acc;
    }
}

extern "C" void kernel_launch(void* const* d_in, const int* in_sizes, int n_in,
                              void* d_out, int out_size, void* d_ws, size_t ws_size,
                              hipStream_t stream) {
    const float* q  = (const float*)d_in[0];
    const float* k  = (const float*)d_in[1];
    const float* v  = (const float*)d_in[2];
    const float* qw = (const float*)d_in[3];
    const float* qb = (const float*)d_in[4];
    const float* kw = (const float*)d_in[5];
    const float* kb = (const float*)d_in[6];
    /* d_in[7] = top_k (always 16; compile-time) */
    float* out = (float*)d_out;
    float* w9  = (float*)d_ws;

    hipLaunchKernelGGL(setup_kernel, dim3(1), dim3(64), 0, stream,
                       qw, qb, kw, kb, w9);
    hipLaunchKernelGGL(bev_main, dim3(NB * NQ / (G * NWAVE)), dim3(BLK),
                       0, stream, q, k, v, w9, out);
}

// Round 9
// 66.132 us; speedup vs baseline: 1.5778x; 1.5778x over previous
//
#include <hip/hip_runtime.h>
#include <stdint.h>

typedef uint64_t u64;
typedef uint32_t u32;

#define NB    8
#define NQ    4096
#define NKEY  4096
#define CV    64
#define KSEL  16
#define G     4              /* queries per wave */
#define NWAVE 2              /* waves per block */
#define BLK   (NWAVE * 64)   /* 128 threads */
#define QPB   (G * NWAVE)    /* 8 queries per block */
#define CMAX  64             /* candidate slots per query */
#define PADU  (~(u64)0)

__device__ __forceinline__ u64 shflxor_u64(u64 v, int m) {
    const u32 lo = __shfl_xor((int)(u32)v, m);
    const u32 hi = __shfl_xor((int)(u32)(v >> 32), m);
    return (((u64)hi) << 32) | lo;
}
__device__ __forceinline__ int mbcnt64(u64 m) {
    return (int)__builtin_amdgcn_mbcnt_hi((u32)(m >> 32),
               __builtin_amdgcn_mbcnt_lo((u32)m, 0));
}
/* monotone float -> u32 key (metric k2-2q.k can be negative) */
__device__ __forceinline__ u32 fkey(float f) {
    const u32 b = __float_as_uint(f);
    return b ^ (0x80000000u | (u32)((int32_t)b >> 31));
}

/* full 64-lane bitonic sort, ascending (threshold order-statistic) */
__device__ __forceinline__ float lanesort64_f32(float v, int lane) {
#pragma unroll
    for (int k = 2; k <= 64; k <<= 1) {
#pragma unroll
        for (int j = k >> 1; j > 0; j >>= 1) {
            const float p = __shfl_xor(v, j);
            const bool up    = ((lane & k) == 0);
            const bool lower = ((lane & j) == 0);
            v = (lower == up) ? fminf(v, p) : fmaxf(v, p);
        }
    }
    return v;
}

/* EXACT smallest-16 SET of 64 lane values -> lanes 0..15.
   sort16/group (alt dirs) -> xor16 half-clean -> merge16 asc/desc -> xor32. */
__device__ __forceinline__ u64 top16of64(u64 v, int lane) {
#pragma unroll
    for (int k = 2; k <= 16; k <<= 1) {
#pragma unroll
        for (int j = k >> 1; j > 0; j >>= 1) {
            const u64 p = shflxor_u64(v, j);
            const bool up    = ((lane & k) == 0);
            const bool lower = ((lane & j) == 0);
            const u64 mn = v < p ? v : p, mx = v < p ? p : v;
            v = (lower == up) ? mn : mx;
        }
    }
    {   const u64 p = shflxor_u64(v, 16);
        const u64 mn = v < p ? v : p, mx = v < p ? p : v;
        v = ((lane & 16) == 0) ? mn : mx; }
#pragma unroll
    for (int j = 8; j > 0; j >>= 1) {
        const u64 p = shflxor_u64(v, j);
        const bool lower = ((lane & j) == 0);
        const bool dasc  = ((lane & 32) == 0);
        const u64 mn = v < p ? v : p, mx = v < p ? p : v;
        v = (lower == dasc) ? mn : mx;
    }
    {   const u64 p = shflxor_u64(v, 32);
        const u64 mn = v < p ? v : p, mx = v < p ? p : v;
        v = ((lane & 32) == 0) ? mn : mx; }
    return v;
}

/* cold overflow fallback (~never; one code copy, uniform branch):
   exact rank-16 threshold via bit binary search, then recollect. */
__device__ __noinline__ int exact_recollect(const float4* __restrict__ kp4,
                                            int lane, float m2xq, float m2yq,
                                            u64* __restrict__ row) {
    u32 lo = 0, hi = ~0u;
#pragma unroll 1
    while (lo < hi) {
        const u32 mid = lo + ((hi - lo) >> 1);
        int cc = 0;
#pragma unroll 1
        for (int c = 0; c < 32; ++c) {
            const float4 kk = kp4[c * 64 + lane];
            const float k2a = fmaf(kk.x, kk.x, kk.y * kk.y);
            const float k2b = fmaf(kk.z, kk.z, kk.w * kk.w);
            const float va = fmaf(kk.x, m2xq, fmaf(kk.y, m2yq, k2a));
            const float vb = fmaf(kk.z, m2xq, fmaf(kk.w, m2yq, k2b));
            cc += (fkey(va) <= mid) ? 1 : 0;
            cc += (fkey(vb) <= mid) ? 1 : 0;
        }
#pragma unroll 1
        for (int off = 32; off; off >>= 1) cc += __shfl_xor(cc, off);
        if (cc >= KSEL) hi = mid; else lo = mid + 1;
    }
    int cc = 0;
#pragma unroll 1
    for (int c = 0; c < 32; ++c) {
        const float4 kk = kp4[c * 64 + lane];
        const float k2a = fmaf(kk.x, kk.x, kk.y * kk.y);
        const float k2b = fmaf(kk.z, kk.z, kk.w * kk.w);
        const float va = fmaf(kk.x, m2xq, fmaf(kk.y, m2yq, k2a));
        const float vb = fmaf(kk.z, m2xq, fmaf(kk.w, m2yq, k2b));
        const u32 ta = fkey(va), tb = fkey(vb);
        const bool aa = ta <= lo, ab = tb <= lo;
        const u64 mka = __ballot(aa);
        const u64 mkb = __ballot(ab);
        const int posa = cc + mbcnt64(mka);
        cc += (int)__popcll(mka);
        const int posb = cc + mbcnt64(mkb);
        cc += (int)__popcll(mkb);
        const u32 ia = (u32)(2 * (c * 64 + lane));
        if (aa && posa < CMAX) row[posa] = (((u64)ta) << 32) | ia;
        if (ab && posb < CMAX) row[posb] = (((u64)tb) << 32) | (ia + 1);
    }
    return cc < CMAX ? cc : CMAX;
}

/* setup: 9 query-independent affine sums over H=64 -> d_ws */
__global__ void setup_kernel(const float* __restrict__ qw, const float* __restrict__ qb,
                             const float* __restrict__ kw, const float* __restrict__ kb,
                             float* __restrict__ w9)
{
    const int h = threadIdx.x & 63;
    const float2 a = ((const float2*)qw)[h];
    const float2 c = ((const float2*)kw)[h];
    const float qbh = qb[h], kbh = kb[h];
    float s[9] = { a.x * c.x, a.y * c.x, qbh * c.x,
                   a.x * c.y, a.y * c.y, qbh * c.y,
                   a.x * kbh, a.y * kbh, qbh * kbh };
#pragma unroll
    for (int i = 0; i < 9; ++i)
#pragma unroll
        for (int off = 32; off; off >>= 1) s[i] += __shfl_xor(s[i], off);
    if (h == 0) {
#pragma unroll
        for (int i = 0; i < 9; ++i) w9[i] = s[i];
    }
}

extern "C" __global__ __launch_bounds__(BLK, 8) void bev_main(
    const float* __restrict__ qg, const float* __restrict__ kg,
    const float* __restrict__ vg, const float* __restrict__ w9,
    float* __restrict__ outg)
{
    __shared__ u64 cand[NWAVE][G][CMAX];      /* 4 KB; per-wave private */
    __shared__ int scnt[NWAVE][G];

    const int tid  = threadIdx.x;
    const int wv   = tid >> 6;
    const int lane = tid & 63;
    const int wvu  = __builtin_amdgcn_readfirstlane(wv);
    const int b    = blockIdx.x >> 9;                  /* 512 blocks per batch */
    const int qbase = ((int)(blockIdx.x & 511) * NWAVE + wvu) * G;

    const float2* kp  = (const float2*)(kg + (size_t)b * NKEY * 2);
    const float4* kp4 = (const float4*)kp;             /* 2 keys / 16 B */
    const float2* qp  = (const float2*)qg + (size_t)b * NQ + qbase;

    /* wave-uniform query coefs (compile-time q index -> stays in SGPR/VGPR) */
    float m2x[G], m2y[G];
#pragma unroll
    for (int q = 0; q < G; ++q) {
        const float2 qc = qp[q];
        m2x[q] = -2.f * qc.x; m2y[q] = -2.f * qc.y;
    }

    /* ---- pass 1: per-lane metric-min per query (shared key loads) ---- */
    float mn[G];
#pragma unroll
    for (int q = 0; q < G; ++q) mn[q] = __builtin_inff();
#pragma unroll 8
    for (int c = 0; c < 32; ++c) {
        const float4 kk = kp4[c * 64 + lane];
        const float k2a = fmaf(kk.x, kk.x, kk.y * kk.y);
        const float k2b = fmaf(kk.z, kk.z, kk.w * kk.w);
#pragma unroll
        for (int q = 0; q < G; ++q) {
            const float va = fmaf(kk.x, m2x[q], fmaf(kk.y, m2y[q], k2a));
            const float vb = fmaf(kk.z, m2x[q], fmaf(kk.w, m2y[q], k2b));
            mn[q] = fminf(fminf(va, vb), mn[q]);
        }
    }

    /* ---- thresholds: 16th-smallest of 64 lane-mins (guarantees >=16) ---- */
    float thr[G];
#pragma unroll
    for (int q = 0; q < G; ++q)
        thr[q] = __shfl(lanesort64_f32(mn[q], lane), 15);

    /* ---- pass 2: recompute metric, ballot-append all <= thr ---- */
    int cnt[G];
#pragma unroll
    for (int q = 0; q < G; ++q) cnt[q] = 0;
#pragma unroll 4
    for (int c = 0; c < 32; ++c) {
        const float4 kk = kp4[c * 64 + lane];
        const float k2a = fmaf(kk.x, kk.x, kk.y * kk.y);
        const float k2b = fmaf(kk.z, kk.z, kk.w * kk.w);
        const u32 ia = (u32)(2 * (c * 64 + lane));
#pragma unroll
        for (int q = 0; q < G; ++q) {
            const float va = fmaf(kk.x, m2x[q], fmaf(kk.y, m2y[q], k2a));
            const float vb = fmaf(kk.z, m2x[q], fmaf(kk.w, m2y[q], k2b));
            const bool aa = va <= thr[q];
            const bool ab = vb <= thr[q];
            const u64 mka = __ballot(aa);
            const u64 mkb = __ballot(ab);
            if (mka | mkb) {                           /* uniform branch */
                const int posa = cnt[q] + mbcnt64(mka);
                cnt[q] += (int)__popcll(mka);
                const int posb = cnt[q] + mbcnt64(mkb);
                cnt[q] += (int)__popcll(mkb);
                if (aa && posa < CMAX)
                    cand[wv][q][posa] = (((u64)fkey(va)) << 32) | ia;
                if (ab && posb < CMAX)
                    cand[wv][q][posb] = (((u64)fkey(vb)) << 32) | (ia + 1);
            }
        }
    }
    if (lane == 0) {
#pragma unroll
        for (int q = 0; q < G; ++q) scnt[wv][q] = cnt[q];
    }

    /* ---- per query: exact top-16, affine scores, softmax, V gather ---- */
    const float s1 = w9[0], s2 = w9[1], s3 = w9[2];
    const float s4 = w9[3], s5 = w9[4], s6 = w9[5];
    const float s7 = w9[6], s8 = w9[7], s9 = w9[8];
    const float* vb = vg + (size_t)b * NKEY * CV;

#pragma unroll 1
    for (int q = 0; q < G; ++q) {
        const float2 qc = qp[q];                       /* uniform reload */
        int cn = scnt[wv][q];
        if (cn > CMAX)                                 /* ~never */
            cn = exact_recollect(kp4, lane, -2.f * qc.x, -2.f * qc.y,
                                 &cand[wv][q][0]);

        u64 myv = (lane < cn) ? cand[wv][q][lane] : PADU;
        myv = top16of64(myv, lane);
        const u32 myidx = (u32)myv;

        const float A  = fmaf(qc.x, s1, fmaf(qc.y, s2, s3));
        const float Bb = fmaf(qc.x, s4, fmaf(qc.y, s5, s6));
        const float Cc = fmaf(qc.x, s7, fmaf(qc.y, s8, s9));

        const int sel = (lane < KSEL) ? (int)myidx : 0;
        const float2 kc = kp[sel];
        const float score = fmaf(A, kc.x, fmaf(Bb, kc.y, Cc));
        float mx = score;
#pragma unroll
        for (int off = 8; off; off >>= 1) mx = fmaxf(mx, __shfl_xor(mx, off));
        const float e = __expf(score - mx);
        float sum = e;
#pragma unroll
        for (int off = 8; off; off >>= 1) sum += __shfl_xor(sum, off);
        const float w = e / sum;                       /* valid lanes 0..15 */

        float acc = 0.f;
#pragma unroll
        for (int s = 0; s < KSEL; ++s) {
            const u32 id   = (u32)__builtin_amdgcn_readlane((int)myidx, s);
            const float ws = __uint_as_float(
                (u32)__builtin_amdgcn_readlane((int)__float_as_uint(w), s));
            acc = fmaf(ws, vb[(size_t)id * CV + lane], acc);
        }
        outg[((size_t)b * NQ + qbase + q) * CV + lane] = acc;
    }
}

extern "C" void kernel_launch(void* const* d_in, const int* in_sizes, int n_in,
                              void* d_out, int out_size, void* d_ws, size_t ws_size,
                              hipStream_t stream) {
    const float* q  = (const float*)d_in[0];
    const float* k  = (const float*)d_in[1];
    const float* v  = (const float*)d_in[2];
    const float* qw = (const float*)d_in[3];
    const float* qb = (const float*)d_in[4];
    const float* kw = (const float*)d_in[5];
    const float* kb = (const float*)d_in[6];
    /* d_in[7] = top_k (always 16; compile-time) */
    float* out = (float*)d_out;
    float* w9  = (float*)d_ws;

    hipLaunchKernelGGL(setup_kernel, dim3(1), dim3(64), 0, stream,
                       qw, qb, kw, kb, w9);
    hipLaunchKernelGGL(bev_main, dim3(NB * NQ / QPB), dim3(BLK),
                       0, stream, q, k, v, w9, out);
}